// Round 14
// baseline (149.083 us; speedup 1.0000x reference)
//
#include <hip/hip_runtime.h>
#include <hip/hip_fp16.h>

// LightGCN propagation, CSR-by-destination formulation.
// N=100000 nodes, D=64 dims, E=1250000 edges (sizes read from in_sizes).
//
// R14 changes vs R13 (props only; build byte-identical for attribution):
//  - k_prop: 8 lanes/node x float4 (16B/lane, same 128B/row) instead of
//    16 lanes x float2. Halves gather + meta instructions, 2x edges in
//    flight/wave. Rationale: prop arithmetic shows ~59 cy per gather
//    instruction while TCP (~8), latency-MLP (~6x headroom) and TCC line
//    throughput all allow much more -> per-instruction issue cost suspected.
//    If null: fabric random-gather floor -> roofline.
// Kept: 3-kernel build (SH=8, LDS-staged bfinal), q15 meta, fp16 z, fused
// z0 + fused final.

#define G 256        // edge-chunk blocks for hist/scatter
#define SH 8         // bucket = dst >> SH
#define BNODES 256   // nodes per bucket
#define CAP 6144     // max staged edges per bucket (48KB LDS)
#define WINV (1.0f / 32767.0f)

// ---------- P1: per-chunk LDS histogram + chunk-base reservation ----------
__global__ void __launch_bounds__(256) k_hist(const int* __restrict__ ei,
                                              unsigned int* __restrict__ gcur,
                                              int* __restrict__ chunkbase,
                                              int NB, int E) {
    extern __shared__ unsigned int hist[];  // NB counters
    int g = blockIdx.x, t = threadIdx.x;
    for (int b = t; b < NB; b += 256) hist[b] = 0;
    __syncthreads();
    int chunk = (E + G - 1) / G;
    int lo = g * chunk;
    int hi = min(lo + chunk, E);
    for (int i = lo + t; i < hi; i += 256) {
        int d = ei[E + i];
        atomicAdd(&hist[d >> SH], 1u);
    }
    __syncthreads();
    for (int b = t; b < NB; b += 256) {
        unsigned h = hist[b];
        unsigned base = atomicAdd(&gcur[b], h);  // 100K returning atomics total
        chunkbase[(size_t)g * NB + b] = (int)base;
    }
}

// ---------- P2: bucket-sorted scatter; bucket bases re-derived in-block -----
__global__ void __launch_bounds__(512) k_bscatter(const int* __restrict__ ei,
                                                  const float* __restrict__ ea,
                                                  const unsigned int* __restrict__ gcur,
                                                  const int* __restrict__ chunkbase,
                                                  int2* __restrict__ ebuf, int NB, int E) {
    __shared__ int tot[512];
    extern __shared__ unsigned int cur[];  // NB cursors
    int g = blockIdx.x, t = threadIdx.x;
    // inclusive scan of gcur over 512 slots (NB <= 512)
    tot[t] = (t < NB) ? (int)gcur[t] : 0;
    __syncthreads();
    for (int off = 1; off < 512; off <<= 1) {
        int x = (t >= off) ? tot[t - off] : 0;
        __syncthreads();
        tot[t] += x;
        __syncthreads();
    }
    for (int b = t; b < NB; b += 512)
        cur[b] = (unsigned)(tot[b] - (int)gcur[b] + chunkbase[(size_t)g * NB + b]);
    __syncthreads();
    int chunk = (E + G - 1) / G;
    int lo = g * chunk;
    int hi = min(lo + chunk, E);
    for (int i = lo + t; i < hi; i += 512) {
        int srcv = ei[i];
        int d = ei[E + i];
        float w = ea[i];
        unsigned pos = atomicAdd(&cur[d >> SH], 1u);
        int2 m;
        m.x = srcv | ((d & (BNODES - 1)) << 17);  // src < 2^17, dlow bits 17..24
        m.y = __float_as_int(w);
        ebuf[pos] = m;
    }
}

// ---------- P3: per-bucket node sort -> meta(u32), row_start, dinv, z0 ------
__global__ void __launch_bounds__(512) k_bfinal(const int2* __restrict__ ebuf,
                                                const unsigned int* __restrict__ gcur,
                                                const float2* __restrict__ emb2,
                                                unsigned int* __restrict__ meta,
                                                int* __restrict__ row_start,
                                                float* __restrict__ dinv,
                                                __half2* __restrict__ z0,
                                                int NB, int N, int E) {
    __shared__ int tot[512];
    __shared__ int2 estage[CAP];
    __shared__ unsigned int hcnt[BNODES];
    __shared__ int sbuf[BNODES];
    __shared__ unsigned int cur2[BNODES];
    __shared__ unsigned int hq[BNODES];
    __shared__ float sdv[BNODES];
    int b = blockIdx.x, t = threadIdx.x;

    // inclusive scan of gcur over 512 slots -> bucket edge range [e0, e1)
    tot[t] = (t < NB) ? (int)gcur[t] : 0;
    __syncthreads();
    for (int off = 1; off < 512; off <<= 1) {
        int x = (t >= off) ? tot[t - off] : 0;
        __syncthreads();
        tot[t] += x;
        __syncthreads();
    }
    int e1 = tot[b];
    int e0 = e1 - (int)gcur[b];
    int cnt = e1 - e0;

    if (t < BNODES) {
        hcnt[t] = 0;
        hq[t] = 0;
    }
    __syncthreads();

    if (cnt <= CAP) {
        // ---- fast path: single global read of ebuf, all passes on LDS ----
        for (int i = t; i < cnt; i += 512) estage[i] = ebuf[e0 + i];
        __syncthreads();
        for (int i = t; i < cnt; i += 512) {
            int2 m = estage[i];
            int dl = (m.x >> 17) & (BNODES - 1);
            float w = __int_as_float(m.y);
            unsigned q = (unsigned)__float2int_rn(w * 32767.0f);
            q = min(q, 32767u);
            atomicAdd(&hcnt[dl], 1u);
            atomicAdd(&hq[dl], q);
        }
        __syncthreads();
        if (t < BNODES) sbuf[t] = (int)hcnt[t];
        __syncthreads();
        for (int off = 1; off < BNODES; off <<= 1) {
            int x = (t < BNODES && t >= off) ? sbuf[t - off] : 0;
            __syncthreads();
            if (t < BNODES) sbuf[t] += x;
            __syncthreads();
        }
        int node = (b << SH) + t;
        if (t < BNODES) {
            int excl = sbuf[t] - (int)hcnt[t];
            cur2[t] = (unsigned)excl;
            float s = (float)hq[t] * WINV;
            float dv = (s > 0.0f) ? rsqrtf(s) : 0.0f;
            sdv[t] = dv;
            if (node < N) {
                row_start[node] = e0 + excl;
                dinv[node] = dv;
            }
        }
        __syncthreads();
        for (int i = t; i < cnt; i += 512) {
            int2 m = estage[i];
            int dl = (m.x >> 17) & (BNODES - 1);
            unsigned p = atomicAdd(&cur2[dl], 1u);
            float w = __int_as_float(m.y);
            unsigned q = (unsigned)__float2int_rn(w * 32767.0f);
            q = min(q, 32767u);
            meta[e0 + (int)p] = (unsigned)(m.x & ((1 << 17) - 1)) | (q << 17);
        }
    } else {
        // ---- fallback (block-uniform branch): two global passes ----
        for (int i = e0 + t; i < e1; i += 512) {
            int2 m = ebuf[i];
            int dl = (m.x >> 17) & (BNODES - 1);
            float w = __int_as_float(m.y);
            unsigned q = (unsigned)__float2int_rn(w * 32767.0f);
            q = min(q, 32767u);
            atomicAdd(&hcnt[dl], 1u);
            atomicAdd(&hq[dl], q);
        }
        __syncthreads();
        if (t < BNODES) sbuf[t] = (int)hcnt[t];
        __syncthreads();
        for (int off = 1; off < BNODES; off <<= 1) {
            int x = (t < BNODES && t >= off) ? sbuf[t - off] : 0;
            __syncthreads();
            if (t < BNODES) sbuf[t] += x;
            __syncthreads();
        }
        int node = (b << SH) + t;
        if (t < BNODES) {
            int excl = sbuf[t] - (int)hcnt[t];
            cur2[t] = (unsigned)excl;
            float s = (float)hq[t] * WINV;
            float dv = (s > 0.0f) ? rsqrtf(s) : 0.0f;
            sdv[t] = dv;
            if (node < N) {
                row_start[node] = e0 + excl;
                dinv[node] = dv;
            }
        }
        __syncthreads();
        for (int i = e0 + t; i < e1; i += 512) {
            int2 m = ebuf[i];
            int dl = (m.x >> 17) & (BNODES - 1);
            unsigned p = atomicAdd(&cur2[dl], 1u);
            float w = __int_as_float(m.y);
            unsigned q = (unsigned)__float2int_rn(w * 32767.0f);
            q = min(q, 32767u);
            meta[e0 + (int)p] = (unsigned)(m.x & ((1 << 17) - 1)) | (q << 17);
        }
    }
    if (b == 0 && t == 0) row_start[N] = E;
    __syncthreads();
    // fused z0 = fp16(emb * dinv): 256 nodes x 32 half2, coalesced
    int base = b << SH;
    for (int idx = t; idx < BNODES * 32; idx += 512) {
        int nd = idx >> 5;
        int gnode = base + nd;
        if (gnode < N) {
            float sc = sdv[nd];
            float2 v = emb2[(size_t)gnode * 32 + (idx & 31)];
            z0[(size_t)gnode * 32 + (idx & 31)] = __floats2half2_rn(v.x * sc, v.y * sc);
        }
    }
}

union F4H {
    float4 f;
    __half2 h[4];
};

// ---------- propagation: x_new = dinv * sum(w * z[src]); z_new = dinv*x_new ----
// 8-lane group per destination node; lane l owns dims 8l..8l+7 (float4 = 4
// half2 = 16B/lane; row = 128B, same as before with HALF the instructions).
// MODE 0: write zout = dinv^2*acc.   MODE 1 (last layer, fused final):
//   out = 0.25*(emb + rd*z1 + rd*z2 + sd*acc), rd = 1/dinv.
template <int MODE>
__global__ void __launch_bounds__(256) k_prop(const float4* __restrict__ zin,   // N*8 float4
                                              const unsigned int* __restrict__ meta,
                                              const int* __restrict__ row_start,
                                              const float* __restrict__ dinv,
                                              float4* __restrict__ zout,        // N*8 float4
                                              const float4* __restrict__ emb,   // N*16 float4
                                              const float4* __restrict__ z1,    // N*8 float4
                                              const float4* __restrict__ z2,    // N*8 float4
                                              float4* __restrict__ out, int N) {
    int g = (blockIdx.x * 256 + threadIdx.x) >> 3;
    if (g >= N) return;
    int l = threadIdx.x & 7;
    int b = row_start[g];
    int e = row_start[g + 1];

    float acc[8] = {0.f, 0.f, 0.f, 0.f, 0.f, 0.f, 0.f, 0.f};
    int i = b;
    for (; i + 8 <= e; i += 8) {
        unsigned mm[8];
        F4H uu[8];
        #pragma unroll
        for (int k = 0; k < 8; ++k) mm[k] = meta[i + k];
        #pragma unroll
        for (int k = 0; k < 8; ++k) uu[k].f = zin[(size_t)(mm[k] & 0x1FFFFu) * 8 + l];
        #pragma unroll
        for (int k = 0; k < 8; ++k) {
            float w = (float)(mm[k] >> 17) * WINV;
            #pragma unroll
            for (int j = 0; j < 4; ++j) {
                float2 a = __half22float2(uu[k].h[j]);
                acc[2 * j]     = fmaf(a.x, w, acc[2 * j]);
                acc[2 * j + 1] = fmaf(a.y, w, acc[2 * j + 1]);
            }
        }
    }
    for (; i < e; ++i) {
        unsigned m = meta[i];
        F4H u;
        u.f = zin[(size_t)(m & 0x1FFFFu) * 8 + l];
        float w = (float)(m >> 17) * WINV;
        #pragma unroll
        for (int j = 0; j < 4; ++j) {
            float2 a = __half22float2(u.h[j]);
            acc[2 * j]     = fmaf(a.x, w, acc[2 * j]);
            acc[2 * j + 1] = fmaf(a.y, w, acc[2 * j + 1]);
        }
    }

    float sd = dinv[g];
    if (MODE == 0) {
        float s2 = sd * sd;
        F4H u;
        #pragma unroll
        for (int j = 0; j < 4; ++j)
            u.h[j] = __floats2half2_rn(s2 * acc[2 * j], s2 * acc[2 * j + 1]);
        zout[g * 8 + l] = u.f;
    } else {
        float rd = (sd > 0.0f) ? (1.0f / sd) : 0.0f;
        F4H u1, u2;
        u1.f = z1[g * 8 + l];
        u2.f = z2[g * 8 + l];
        float4 ev0 = emb[g * 16 + 2 * l];
        float4 ev1 = emb[g * 16 + 2 * l + 1];
        float2 p0 = __half22float2(u1.h[0]), q0 = __half22float2(u2.h[0]);
        float2 p1 = __half22float2(u1.h[1]), q1 = __half22float2(u2.h[1]);
        float2 p2 = __half22float2(u1.h[2]), q2 = __half22float2(u2.h[2]);
        float2 p3 = __half22float2(u1.h[3]), q3 = __half22float2(u2.h[3]);
        float4 r0, r1;
        r0.x = 0.25f * (ev0.x + rd * (p0.x + q0.x) + sd * acc[0]);
        r0.y = 0.25f * (ev0.y + rd * (p0.y + q0.y) + sd * acc[1]);
        r0.z = 0.25f * (ev0.z + rd * (p1.x + q1.x) + sd * acc[2]);
        r0.w = 0.25f * (ev0.w + rd * (p1.y + q1.y) + sd * acc[3]);
        r1.x = 0.25f * (ev1.x + rd * (p2.x + q2.x) + sd * acc[4]);
        r1.y = 0.25f * (ev1.y + rd * (p2.y + q2.y) + sd * acc[5]);
        r1.z = 0.25f * (ev1.z + rd * (p3.x + q3.x) + sd * acc[6]);
        r1.w = 0.25f * (ev1.w + rd * (p3.y + q3.y) + sd * acc[7]);
        out[g * 16 + 2 * l] = r0;
        out[g * 16 + 2 * l + 1] = r1;
    }
}

static inline size_t align_up(size_t x, size_t a) { return (x + a - 1) & ~(a - 1); }

extern "C" void kernel_launch(void* const* d_in, const int* in_sizes, int n_in,
                              void* d_out, int out_size, void* d_ws, size_t ws_size,
                              hipStream_t stream) {
    const float* emb = (const float*)d_in[0];
    const float* ea  = (const float*)d_in[1];
    const int*   ei  = (const int*)d_in[2];
    float* out = (float*)d_out;

    const int D = 64;
    const int N = in_sizes[0] / D;
    const int E = in_sizes[1];

    const int NB = (N + BNODES - 1) / BNODES;   // 391 for N=100000 (must be <=512)

    // workspace carve (all 256B-aligned)
    char* ws = (char*)d_ws;
    size_t off = 0;
    unsigned int* gcur = (unsigned int*)(ws + off);
                                            off = align_up(off + (size_t)NB * 4, 256);
    int* chunkbase = (int*)(ws + off);      off = align_up(off + (size_t)G * NB * 4, 256);
    int* row_start = (int*)(ws + off);      off = align_up(off + (size_t)(N + 1) * 4, 256);
    float* dinv = (float*)(ws + off);       off = align_up(off + (size_t)N * 4, 256);
    int2* ebuf = (int2*)(ws + off);         off = align_up(off + (size_t)E * 8, 256);
    unsigned int* meta = (unsigned int*)(ws + off); off = align_up(off + (size_t)E * 4, 256);
    __half2* z0 = (__half2*)(ws + off);     off = align_up(off + (size_t)N * D * 2, 256);
    __half2* z1 = (__half2*)(ws + off);     off = align_up(off + (size_t)N * D * 2, 256);
    __half2* z2 = (__half2*)(ws + off);     off = align_up(off + (size_t)N * D * 2, 256);
    (void)ws_size;

    // ---- CSR build: 3 kernels + tiny memset ----
    hipMemsetAsync(gcur, 0, (size_t)NB * 4, stream);
    k_hist<<<G, 256, NB * 4, stream>>>(ei, gcur, chunkbase, NB, E);
    k_bscatter<<<G, 512, NB * 4, stream>>>(ei, ea, gcur, chunkbase, ebuf, NB, E);
    k_bfinal<<<NB, 512, 0, stream>>>(ebuf, gcur, (const float2*)emb, meta, row_start,
                                     dinv, z0, NB, N, E);

    // ---- propagation (8 lanes/node) ----
    int lb = (N * 8 + 255) / 256;
    k_prop<0><<<lb, 256, 0, stream>>>((const float4*)z0, meta, row_start, dinv,
                                      (float4*)z1, nullptr, nullptr, nullptr, nullptr, N);
    k_prop<0><<<lb, 256, 0, stream>>>((const float4*)z1, meta, row_start, dinv,
                                      (float4*)z2, nullptr, nullptr, nullptr, nullptr, N);
    k_prop<1><<<lb, 256, 0, stream>>>((const float4*)z2, meta, row_start, dinv,
                                      nullptr, (const float4*)emb, (const float4*)z1,
                                      (const float4*)z2, (float4*)out, N);
}

// Round 15
// 140.903 us; speedup vs baseline: 1.0581x; 1.0581x over previous
//
#include <hip/hip_runtime.h>
#include <hip/hip_fp16.h>

// LightGCN propagation, CSR-by-destination formulation.
// N=100000 nodes, D=64 dims, E=1250000 edges (sizes read from in_sizes).
//
// R15 = R13 exact revert (best: 139.6us). R14's 8-lane float4 props regressed
// (149.1): fewer/fatter gather instructions lose to the 16-lane float2 form --
// the props are at the fabric's random-128B-gather service floor, not
// instruction-issue bound. Build: 3 kernels (SH=8, LDS-staged bfinal), q15
// meta, fp16 z, fused z0 + fused final.

#define G 256        // edge-chunk blocks for hist/scatter
#define SH 8         // bucket = dst >> SH
#define BNODES 256   // nodes per bucket
#define CAP 6144     // max staged edges per bucket (48KB LDS)
#define WINV (1.0f / 32767.0f)

// ---------- P1: per-chunk LDS histogram + chunk-base reservation ----------
__global__ void __launch_bounds__(256) k_hist(const int* __restrict__ ei,
                                              unsigned int* __restrict__ gcur,
                                              int* __restrict__ chunkbase,
                                              int NB, int E) {
    extern __shared__ unsigned int hist[];  // NB counters
    int g = blockIdx.x, t = threadIdx.x;
    for (int b = t; b < NB; b += 256) hist[b] = 0;
    __syncthreads();
    int chunk = (E + G - 1) / G;
    int lo = g * chunk;
    int hi = min(lo + chunk, E);
    for (int i = lo + t; i < hi; i += 256) {
        int d = ei[E + i];
        atomicAdd(&hist[d >> SH], 1u);
    }
    __syncthreads();
    for (int b = t; b < NB; b += 256) {
        unsigned h = hist[b];
        unsigned base = atomicAdd(&gcur[b], h);  // 100K returning atomics total
        chunkbase[(size_t)g * NB + b] = (int)base;
    }
}

// ---------- P2: bucket-sorted scatter; bucket bases re-derived in-block -----
__global__ void __launch_bounds__(512) k_bscatter(const int* __restrict__ ei,
                                                  const float* __restrict__ ea,
                                                  const unsigned int* __restrict__ gcur,
                                                  const int* __restrict__ chunkbase,
                                                  int2* __restrict__ ebuf, int NB, int E) {
    __shared__ int tot[512];
    extern __shared__ unsigned int cur[];  // NB cursors
    int g = blockIdx.x, t = threadIdx.x;
    // inclusive scan of gcur over 512 slots (NB <= 512)
    tot[t] = (t < NB) ? (int)gcur[t] : 0;
    __syncthreads();
    for (int off = 1; off < 512; off <<= 1) {
        int x = (t >= off) ? tot[t - off] : 0;
        __syncthreads();
        tot[t] += x;
        __syncthreads();
    }
    for (int b = t; b < NB; b += 512)
        cur[b] = (unsigned)(tot[b] - (int)gcur[b] + chunkbase[(size_t)g * NB + b]);
    __syncthreads();
    int chunk = (E + G - 1) / G;
    int lo = g * chunk;
    int hi = min(lo + chunk, E);
    for (int i = lo + t; i < hi; i += 512) {
        int srcv = ei[i];
        int d = ei[E + i];
        float w = ea[i];
        unsigned pos = atomicAdd(&cur[d >> SH], 1u);
        int2 m;
        m.x = srcv | ((d & (BNODES - 1)) << 17);  // src < 2^17, dlow bits 17..24
        m.y = __float_as_int(w);
        ebuf[pos] = m;
    }
}

// ---------- P3: per-bucket node sort -> meta(u32), row_start, dinv, z0 ------
__global__ void __launch_bounds__(512) k_bfinal(const int2* __restrict__ ebuf,
                                                const unsigned int* __restrict__ gcur,
                                                const float2* __restrict__ emb2,
                                                unsigned int* __restrict__ meta,
                                                int* __restrict__ row_start,
                                                float* __restrict__ dinv,
                                                __half2* __restrict__ z0,
                                                int NB, int N, int E) {
    __shared__ int tot[512];
    __shared__ int2 estage[CAP];
    __shared__ unsigned int hcnt[BNODES];
    __shared__ int sbuf[BNODES];
    __shared__ unsigned int cur2[BNODES];
    __shared__ unsigned int hq[BNODES];
    __shared__ float sdv[BNODES];
    int b = blockIdx.x, t = threadIdx.x;

    // inclusive scan of gcur over 512 slots -> bucket edge range [e0, e1)
    tot[t] = (t < NB) ? (int)gcur[t] : 0;
    __syncthreads();
    for (int off = 1; off < 512; off <<= 1) {
        int x = (t >= off) ? tot[t - off] : 0;
        __syncthreads();
        tot[t] += x;
        __syncthreads();
    }
    int e1 = tot[b];
    int e0 = e1 - (int)gcur[b];
    int cnt = e1 - e0;

    if (t < BNODES) {
        hcnt[t] = 0;
        hq[t] = 0;
    }
    __syncthreads();

    if (cnt <= CAP) {
        // ---- fast path: single global read of ebuf, all passes on LDS ----
        for (int i = t; i < cnt; i += 512) estage[i] = ebuf[e0 + i];
        __syncthreads();
        for (int i = t; i < cnt; i += 512) {
            int2 m = estage[i];
            int dl = (m.x >> 17) & (BNODES - 1);
            float w = __int_as_float(m.y);
            unsigned q = (unsigned)__float2int_rn(w * 32767.0f);
            q = min(q, 32767u);
            atomicAdd(&hcnt[dl], 1u);
            atomicAdd(&hq[dl], q);
        }
        __syncthreads();
        if (t < BNODES) sbuf[t] = (int)hcnt[t];
        __syncthreads();
        for (int off = 1; off < BNODES; off <<= 1) {
            int x = (t < BNODES && t >= off) ? sbuf[t - off] : 0;
            __syncthreads();
            if (t < BNODES) sbuf[t] += x;
            __syncthreads();
        }
        int node = (b << SH) + t;
        if (t < BNODES) {
            int excl = sbuf[t] - (int)hcnt[t];
            cur2[t] = (unsigned)excl;
            float s = (float)hq[t] * WINV;
            float dv = (s > 0.0f) ? rsqrtf(s) : 0.0f;
            sdv[t] = dv;
            if (node < N) {
                row_start[node] = e0 + excl;
                dinv[node] = dv;
            }
        }
        __syncthreads();
        for (int i = t; i < cnt; i += 512) {
            int2 m = estage[i];
            int dl = (m.x >> 17) & (BNODES - 1);
            unsigned p = atomicAdd(&cur2[dl], 1u);
            float w = __int_as_float(m.y);
            unsigned q = (unsigned)__float2int_rn(w * 32767.0f);
            q = min(q, 32767u);
            meta[e0 + (int)p] = (unsigned)(m.x & ((1 << 17) - 1)) | (q << 17);
        }
    } else {
        // ---- fallback (block-uniform branch): two global passes ----
        for (int i = e0 + t; i < e1; i += 512) {
            int2 m = ebuf[i];
            int dl = (m.x >> 17) & (BNODES - 1);
            float w = __int_as_float(m.y);
            unsigned q = (unsigned)__float2int_rn(w * 32767.0f);
            q = min(q, 32767u);
            atomicAdd(&hcnt[dl], 1u);
            atomicAdd(&hq[dl], q);
        }
        __syncthreads();
        if (t < BNODES) sbuf[t] = (int)hcnt[t];
        __syncthreads();
        for (int off = 1; off < BNODES; off <<= 1) {
            int x = (t < BNODES && t >= off) ? sbuf[t - off] : 0;
            __syncthreads();
            if (t < BNODES) sbuf[t] += x;
            __syncthreads();
        }
        int node = (b << SH) + t;
        if (t < BNODES) {
            int excl = sbuf[t] - (int)hcnt[t];
            cur2[t] = (unsigned)excl;
            float s = (float)hq[t] * WINV;
            float dv = (s > 0.0f) ? rsqrtf(s) : 0.0f;
            sdv[t] = dv;
            if (node < N) {
                row_start[node] = e0 + excl;
                dinv[node] = dv;
            }
        }
        __syncthreads();
        for (int i = e0 + t; i < e1; i += 512) {
            int2 m = ebuf[i];
            int dl = (m.x >> 17) & (BNODES - 1);
            unsigned p = atomicAdd(&cur2[dl], 1u);
            float w = __int_as_float(m.y);
            unsigned q = (unsigned)__float2int_rn(w * 32767.0f);
            q = min(q, 32767u);
            meta[e0 + (int)p] = (unsigned)(m.x & ((1 << 17) - 1)) | (q << 17);
        }
    }
    if (b == 0 && t == 0) row_start[N] = E;
    __syncthreads();
    // fused z0 = fp16(emb * dinv): 256 nodes x 32 half2, coalesced
    int base = b << SH;
    for (int idx = t; idx < BNODES * 32; idx += 512) {
        int nd = idx >> 5;
        int gnode = base + nd;
        if (gnode < N) {
            float sc = sdv[nd];
            float2 v = emb2[(size_t)gnode * 32 + (idx & 31)];
            z0[(size_t)gnode * 32 + (idx & 31)] = __floats2half2_rn(v.x * sc, v.y * sc);
        }
    }
}

union F2H {
    float2 f;
    __half2 h[2];
};

// ---------- propagation: x_new = dinv * sum(w * z[src]); z_new = dinv*x_new ----
// 16-lane group per destination node; lane l owns dims 4l..4l+3.
// MODE 0: write zout = dinv^2*acc.   MODE 1 (last layer, fused final):
//   out = 0.25*(emb + rd*z1 + rd*z2 + sd*acc), rd = 1/dinv.
template <int MODE>
__global__ void __launch_bounds__(256) k_prop(const float2* __restrict__ zin,
                                              const unsigned int* __restrict__ meta,
                                              const int* __restrict__ row_start,
                                              const float* __restrict__ dinv,
                                              float2* __restrict__ zout,
                                              const float4* __restrict__ emb,
                                              const float2* __restrict__ z1,
                                              const float2* __restrict__ z2,
                                              float4* __restrict__ out, int N) {
    int g = (blockIdx.x * 256 + threadIdx.x) >> 4;
    if (g >= N) return;
    int l = threadIdx.x & 15;
    int b = row_start[g];
    int e = row_start[g + 1];

    float4 acc = make_float4(0.f, 0.f, 0.f, 0.f);
    int i = b;
    for (; i + 8 <= e; i += 8) {
        unsigned mm[8];
        F2H uu[8];
        #pragma unroll
        for (int k = 0; k < 8; ++k) mm[k] = meta[i + k];
        #pragma unroll
        for (int k = 0; k < 8; ++k) uu[k].f = zin[(size_t)(mm[k] & 0x1FFFFu) * 16 + l];
        #pragma unroll
        for (int k = 0; k < 8; ++k) {
            float w = (float)(mm[k] >> 17) * WINV;
            float2 a = __half22float2(uu[k].h[0]), bb = __half22float2(uu[k].h[1]);
            acc.x = fmaf(a.x, w, acc.x);
            acc.y = fmaf(a.y, w, acc.y);
            acc.z = fmaf(bb.x, w, acc.z);
            acc.w = fmaf(bb.y, w, acc.w);
        }
    }
    for (; i + 4 <= e; i += 4) {
        unsigned mm[4];
        F2H uu[4];
        #pragma unroll
        for (int k = 0; k < 4; ++k) mm[k] = meta[i + k];
        #pragma unroll
        for (int k = 0; k < 4; ++k) uu[k].f = zin[(size_t)(mm[k] & 0x1FFFFu) * 16 + l];
        #pragma unroll
        for (int k = 0; k < 4; ++k) {
            float w = (float)(mm[k] >> 17) * WINV;
            float2 a = __half22float2(uu[k].h[0]), bb = __half22float2(uu[k].h[1]);
            acc.x = fmaf(a.x, w, acc.x);
            acc.y = fmaf(a.y, w, acc.y);
            acc.z = fmaf(bb.x, w, acc.z);
            acc.w = fmaf(bb.y, w, acc.w);
        }
    }
    for (; i < e; ++i) {
        unsigned m = meta[i];
        F2H u;
        u.f = zin[(size_t)(m & 0x1FFFFu) * 16 + l];
        float w = (float)(m >> 17) * WINV;
        float2 a = __half22float2(u.h[0]), bb = __half22float2(u.h[1]);
        acc.x = fmaf(a.x, w, acc.x);
        acc.y = fmaf(a.y, w, acc.y);
        acc.z = fmaf(bb.x, w, acc.z);
        acc.w = fmaf(bb.y, w, acc.w);
    }

    float sd = dinv[g];
    int o = g * 16 + l;
    if (MODE == 0) {
        float s2 = sd * sd;
        F2H u;
        u.h[0] = __floats2half2_rn(s2 * acc.x, s2 * acc.y);
        u.h[1] = __floats2half2_rn(s2 * acc.z, s2 * acc.w);
        zout[o] = u.f;
    } else {
        float rd = (sd > 0.0f) ? (1.0f / sd) : 0.0f;
        F2H u1, u2;
        u1.f = z1[o];
        u2.f = z2[o];
        float2 a1 = __half22float2(u1.h[0]), b1 = __half22float2(u1.h[1]);
        float2 a2 = __half22float2(u2.h[0]), b2 = __half22float2(u2.h[1]);
        float4 ev = emb[o];
        float4 r;
        r.x = 0.25f * (ev.x + rd * (a1.x + a2.x) + sd * acc.x);
        r.y = 0.25f * (ev.y + rd * (a1.y + a2.y) + sd * acc.y);
        r.z = 0.25f * (ev.z + rd * (b1.x + b2.x) + sd * acc.z);
        r.w = 0.25f * (ev.w + rd * (b1.y + b2.y) + sd * acc.w);
        out[o] = r;
    }
}

static inline size_t align_up(size_t x, size_t a) { return (x + a - 1) & ~(a - 1); }

extern "C" void kernel_launch(void* const* d_in, const int* in_sizes, int n_in,
                              void* d_out, int out_size, void* d_ws, size_t ws_size,
                              hipStream_t stream) {
    const float* emb = (const float*)d_in[0];
    const float* ea  = (const float*)d_in[1];
    const int*   ei  = (const int*)d_in[2];
    float* out = (float*)d_out;

    const int D = 64;
    const int N = in_sizes[0] / D;
    const int E = in_sizes[1];

    const int NB = (N + BNODES - 1) / BNODES;   // 391 for N=100000 (must be <=512)

    // workspace carve (all 256B-aligned)
    char* ws = (char*)d_ws;
    size_t off = 0;
    unsigned int* gcur = (unsigned int*)(ws + off);
                                            off = align_up(off + (size_t)NB * 4, 256);
    int* chunkbase = (int*)(ws + off);      off = align_up(off + (size_t)G * NB * 4, 256);
    int* row_start = (int*)(ws + off);      off = align_up(off + (size_t)(N + 1) * 4, 256);
    float* dinv = (float*)(ws + off);       off = align_up(off + (size_t)N * 4, 256);
    int2* ebuf = (int2*)(ws + off);         off = align_up(off + (size_t)E * 8, 256);
    unsigned int* meta = (unsigned int*)(ws + off); off = align_up(off + (size_t)E * 4, 256);
    __half2* z0 = (__half2*)(ws + off);     off = align_up(off + (size_t)N * D * 2, 256);
    __half2* z1 = (__half2*)(ws + off);     off = align_up(off + (size_t)N * D * 2, 256);
    __half2* z2 = (__half2*)(ws + off);     off = align_up(off + (size_t)N * D * 2, 256);
    (void)ws_size;

    // ---- CSR build: 3 kernels + tiny memset ----
    hipMemsetAsync(gcur, 0, (size_t)NB * 4, stream);
    k_hist<<<G, 256, NB * 4, stream>>>(ei, gcur, chunkbase, NB, E);
    k_bscatter<<<G, 512, NB * 4, stream>>>(ei, ea, gcur, chunkbase, ebuf, NB, E);
    k_bfinal<<<NB, 512, 0, stream>>>(ebuf, gcur, (const float2*)emb, meta, row_start,
                                     dinv, z0, NB, N, E);

    // ---- propagation ----
    int lb = (N * 16 + 255) / 256;
    k_prop<0><<<lb, 256, 0, stream>>>((const float2*)z0, meta, row_start, dinv,
                                      (float2*)z1, nullptr, nullptr, nullptr, nullptr, N);
    k_prop<0><<<lb, 256, 0, stream>>>((const float2*)z1, meta, row_start, dinv,
                                      (float2*)z2, nullptr, nullptr, nullptr, nullptr, N);
    k_prop<1><<<lb, 256, 0, stream>>>((const float2*)z2, meta, row_start, dinv,
                                      nullptr, (const float4*)emb, (const float2*)z1,
                                      (const float2*)z2, (float4*)out, N);
}